// Round 1
// baseline (139.924 us; speedup 1.0000x reference)
//
#include <hip/hip_runtime.h>

typedef unsigned short u16;
typedef __bf16 bf16x8 __attribute__((ext_vector_type(8)));
typedef float f32x4 __attribute__((ext_vector_type(4)));

#define MFMA16(a, b, c) __builtin_amdgcn_mfma_f32_16x16x32_bf16((a), (b), (c), 0, 0, 0)

__device__ __forceinline__ bf16x8 ld8(const u16* p) {
    return *reinterpret_cast<const bf16x8*>(p);
}

__device__ __forceinline__ unsigned pk2(float a, float b) {
    unsigned short ua = __builtin_bit_cast(unsigned short, (__bf16)a);
    unsigned short ub = __builtin_bit_cast(unsigned short, (__bf16)b);
    return (unsigned)ua | ((unsigned)ub << 16);
}

__device__ __forceinline__ bf16x8 cvt8(float4 a, float4 b) {
    bf16x8 r;
    r[0] = (__bf16)a.x; r[1] = (__bf16)a.y; r[2] = (__bf16)a.z; r[3] = (__bf16)a.w;
    r[4] = (__bf16)b.x; r[5] = (__bf16)b.y; r[6] = (__bf16)b.z; r[7] = (__bf16)b.w;
    return r;
}

// ---------------- Kernel 0: convert Wq/Wk/Wv fp32 -> bf16 ----------------
__global__ __launch_bounds__(256) void wcvt_kernel(
    const float* __restrict__ Wq, const float* __restrict__ Wk,
    const float* __restrict__ Wv, u16* __restrict__ wb)
{
    const int t = blockIdx.x * 256 + threadIdx.x;   // 24576 threads, 8 elems each
    const int mat = t >> 13;
    const int idx = (t & 8191) * 8;
    const float* src = (mat == 0) ? Wq : (mat == 1) ? Wk : Wv;
    float4 a = *(const float4*)(src + idx);
    float4 b = *(const float4*)(src + idx + 4);
    uint4 o;
    o.x = pk2(a.x, a.y); o.y = pk2(a.z, a.w);
    o.z = pk2(b.x, b.y); o.w = pk2(b.z, b.w);
    *reinterpret_cast<uint4*>(wb + (size_t)mat * 65536 + idx) = o;
}

// ---------------- Kernel 1: projections q,k (row-major) and v (transposed) ----------------
// grid 384: mat = blockIdx>>7 (0=q,1=k,2=v), 64 rows (or s-cols) per wg, 4 waves x 16.
__global__ __launch_bounds__(256) void proj_kernel(
    const float* __restrict__ Q, const float* __restrict__ K, const float* __restrict__ V,
    const float* __restrict__ bq, const float* __restrict__ bk, const float* __restrict__ bv,
    const u16* __restrict__ wb, u16* __restrict__ qb, u16* __restrict__ kb,
    u16* __restrict__ vtb)
{
    const int mat  = blockIdx.x >> 7;
    const int tile = blockIdx.x & 127;
    const int lane = threadIdx.x & 63;
    const int w    = threadIdx.x >> 6;
    const int c    = lane & 15, g = lane >> 4;

    const float* X = (mat == 0) ? Q : (mat == 1) ? K : V;
    const u16*   W = wb + (size_t)mat * 65536;

    const int rw = tile * 64 + w * 16;                        // row base (q/k) or s base (v)
    const float* xp = X + (size_t)(rw + c) * 1024 + g * 8;    // stream operand, fp32
    const u16*   wp = W + (size_t)c * 1024 + g * 8;           // weight frags, bf16

    f32x4 acc[4] = {};
    float4 xa = *(const float4*)xp;
    float4 xb = *(const float4*)(xp + 4);

    #pragma unroll 2
    for (int kk = 0; kk < 32; ++kk) {
        bf16x8 a = cvt8(xa, xb);
        if (kk < 31) {                                        // depth-1 prefetch of HBM stream
            xa = *(const float4*)(xp + (kk + 1) * 32);
            xb = *(const float4*)(xp + (kk + 1) * 32 + 4);
        }
        const u16* wk = wp + kk * 32;
        if (mat < 2) {
            #pragma unroll
            for (int t = 0; t < 4; ++t)
                acc[t] = MFMA16(a, ld8(wk + t * 16 * 1024), acc[t]);   // D[row=X-row][col=dk]
        } else {
            #pragma unroll
            for (int t = 0; t < 4; ++t)
                acc[t] = MFMA16(ld8(wk + t * 16 * 1024), a, acc[t]);   // D[row=dv][col=s]
        }
    }

    if (mat < 2) {
        const float* bias = (mat == 0) ? bq : bk;
        u16* dst = (mat == 0) ? qb : kb;
        #pragma unroll
        for (int t = 0; t < 4; ++t) {
            const float bz = bias[t * 16 + c];
            #pragma unroll
            for (int r = 0; r < 4; ++r) {
                const int row = rw + g * 4 + r;               // D row = (lane>>4)*4 + reg
                dst[(size_t)row * 64 + t * 16 + c] =
                    __builtin_bit_cast(u16, (__bf16)(acc[t][r] + bz));
            }
        }
    } else {
        const int sg = rw + c;                                 // global V row (s)
        const int bidx = sg >> 12, sin = sg & 4095;
        #pragma unroll
        for (int t = 0; t < 4; ++t) {
            #pragma unroll
            for (int r = 0; r < 4; ++r) {
                const int dv = t * 16 + g * 4 + r;
                vtb[(size_t)(bidx * 64 + dv) * 4096 + sin] =
                    __builtin_bit_cast(u16, (__bf16)(acc[t][r] + bv[dv]));
            }
        }
    }
}

// ---------------- Kernel 2: flash attention phase 1 (per-wave strip x s-chunk) ----------------
// 1024 wgs x 4 waves; wave = (strip of 16 q-rows, chunk of 512 s). Partials to ws.
__global__ __launch_bounds__(256) void attn_kernel(
    const int* __restrict__ mask, const u16* __restrict__ qb,
    const u16* __restrict__ kb, const u16* __restrict__ vtb,
    float* __restrict__ pacc, float* __restrict__ pm, float* __restrict__ pl)
{
    __shared__ uint2 plds[4][128];   // per-wave 16q x 32s bf16, chunk-XOR swizzled
    const int lane = threadIdx.x & 63, w = threadIdx.x >> 6;
    const int c = lane & 15, g = lane >> 4;
    const int gw    = blockIdx.x * 4 + w;
    const int strip = gw >> 3;
    const int chunk = gw & 7;
    const int b     = strip >> 8;
    const int q0    = (strip & 255) * 16;
    const int sBase = chunk * 512;
    const float SSC = 0.18033688011112042f;   // (1/8) * log2(e)

    // q-fragments hoisted for the whole chunk (B operand: col=c=q, k-run=dk)
    const u16* qrow = qb + (size_t)((b << 12) + q0 + c) * 64 + g * 8;
    const bf16x8 qf0 = ld8(qrow);
    const bf16x8 qf1 = ld8(qrow + 32);

    const u16* kbase = kb  + ((size_t)b << 12) * 64;
    const u16* vbase = vtb + (size_t)(b * 64 + c) * 4096;
    const int* mrow  = mask + ((size_t)b << 24) + (size_t)(q0 + c) * 4096 + g * 4;

    f32x4 acc0 = {}, acc1 = {}, acc2 = {}, acc3 = {};
    const f32x4 zf = {};
    float m_run = -__builtin_inff(), l_run = 0.f;

    int4 mk0 = *(const int4*)(mrow + sBase);        // depth-1 mask prefetch (HBM stream)
    int4 mk1 = *(const int4*)(mrow + sBase + 16);

    for (int it = 0; it < 16; ++it) {
        const int s0 = sBase + it * 32;
        // QK^T swapped: D[s][q], two 16-s subtiles, K=64 via 2 chained MFMAs each
        const u16* kp0 = kbase + (size_t)(s0 + c) * 64 + g * 8;
        const u16* kp1 = kp0 + 16 * 64;
        f32x4 d0 = MFMA16(ld8(kp0), qf0, zf);
        d0 = MFMA16(ld8(kp0 + 32), qf1, d0);
        f32x4 d1 = MFMA16(ld8(kp1), qf0, zf);
        d1 = MFMA16(ld8(kp1 + 32), qf1, d1);

        const int4 cm0 = mk0, cm1 = mk1;
        if (it < 15) {
            mk0 = *(const int4*)(mrow + s0 + 32);
            mk1 = *(const int4*)(mrow + s0 + 48);
        }

        // base-2 domain scores; masked -> -1e9 (replicates ref incl. all-masked rows)
        const float x0 = cm0.x ? d0[0] * SSC : -1e9f;
        const float x1 = cm0.y ? d0[1] * SSC : -1e9f;
        const float x2 = cm0.z ? d0[2] * SSC : -1e9f;
        const float x3 = cm0.w ? d0[3] * SSC : -1e9f;
        const float x4 = cm1.x ? d1[0] * SSC : -1e9f;
        const float x5 = cm1.y ? d1[1] * SSC : -1e9f;
        const float x6 = cm1.z ? d1[2] * SSC : -1e9f;
        const float x7 = cm1.w ? d1[3] * SSC : -1e9f;

        float tm = fmaxf(fmaxf(fmaxf(x0, x1), fmaxf(x2, x3)),
                         fmaxf(fmaxf(x4, x5), fmaxf(x6, x7)));
        tm = fmaxf(tm, __shfl_xor(tm, 16));
        tm = fmaxf(tm, __shfl_xor(tm, 32));
        const float m_new = fmaxf(m_run, tm);
        const float f = exp2f(m_run - m_new);      // 1.0 exactly when no update

        const float p0 = exp2f(x0 - m_new), p1 = exp2f(x1 - m_new);
        const float p2 = exp2f(x2 - m_new), p3 = exp2f(x3 - m_new);
        const float p4 = exp2f(x4 - m_new), p5 = exp2f(x5 - m_new);
        const float p6 = exp2f(x6 - m_new), p7 = exp2f(x7 - m_new);
        float rs = ((p0 + p1) + (p2 + p3)) + ((p4 + p5) + (p6 + p7));
        rs += __shfl_xor(rs, 16);
        rs += __shfl_xor(rs, 32);
        l_run = l_run * f + rs;
        m_run = m_new;

        // P -> LDS, row q=c, 8B chunks XOR-swizzled by (q&7): 2-way banks (free)
        plds[w][c * 8 + ( g      ^ (c & 7))] = make_uint2(pk2(p0, p1), pk2(p2, p3));
        plds[w][c * 8 + ((g + 4) ^ (c & 7))] = make_uint2(pk2(p4, p5), pk2(p6, p7));

        if (__any(f < 1.0f)) {                     // acc rescale (rare after warm-up)
            const float f0 = __shfl(f, g * 4 + 0);
            const float f1 = __shfl(f, g * 4 + 1);
            const float f2 = __shfl(f, g * 4 + 2);
            const float f3 = __shfl(f, g * 4 + 3);
            acc0[0] *= f0; acc0[1] *= f1; acc0[2] *= f2; acc0[3] *= f3;
            acc1[0] *= f0; acc1[1] *= f1; acc1[2] *= f2; acc1[3] *= f3;
            acc2[0] *= f0; acc2[1] *= f1; acc2[2] *= f2; acc2[3] *= f3;
            acc3[0] *= f0; acc3[1] *= f1; acc3[2] *= f2; acc3[3] *= f3;
        }

        // PV: A = P[q=c][s-run g*8..g*8+7] from LDS, B = vT (k-contiguous)
        union { uint2 u[2]; bf16x8 v; } pa;
        pa.u[0] = plds[w][c * 8 + ((2 * g    ) ^ (c & 7))];
        pa.u[1] = plds[w][c * 8 + ((2 * g + 1) ^ (c & 7))];

        const u16* vp = vbase + s0 + g * 8;
        acc0 = MFMA16(pa.v, ld8(vp),             acc0);
        acc1 = MFMA16(pa.v, ld8(vp + 16 * 4096), acc1);
        acc2 = MFMA16(pa.v, ld8(vp + 32 * 4096), acc2);
        acc3 = MFMA16(pa.v, ld8(vp + 48 * 4096), acc3);
    }

    const size_t pidx = (size_t)(strip * 8 + chunk) * 16;
    #pragma unroll
    for (int r = 0; r < 4; ++r) {
        const size_t row = pidx + g * 4 + r;
        pacc[row * 64 +  0 + c] = acc0[r];
        pacc[row * 64 + 16 + c] = acc1[r];
        pacc[row * 64 + 32 + c] = acc2[r];
        pacc[row * 64 + 48 + c] = acc3[r];
    }
    if (lane < 16) {
        pm[pidx + c] = m_run;
        pl[pidx + c] = l_run;
    }
}

// ---------------- Kernel 3: combine 8 s-chunk partials per row ----------------
__global__ __launch_bounds__(256) void comb_kernel(
    const float* __restrict__ pacc, const float* __restrict__ pm,
    const float* __restrict__ pl, float* __restrict__ out)
{
    const int t = blockIdx.x * 256 + threadIdx.x;   // 524288 = 8192 rows x 64
    const int r = t >> 6, dv = t & 63;
    const int strip = r >> 4, qi = r & 15;
    const int base = strip * 128 + qi;
    float mv[8];
    float M = -__builtin_inff();
    #pragma unroll
    for (int cc = 0; cc < 8; ++cc) { mv[cc] = pm[base + cc * 16]; M = fmaxf(M, mv[cc]); }
    float num = 0.f, den = 0.f;
    #pragma unroll
    for (int cc = 0; cc < 8; ++cc) {
        const float wgt = exp2f(mv[cc] - M);
        num += wgt * pacc[(size_t)(base + cc * 16) * 64 + dv];
        den += wgt * pl[base + cc * 16];
    }
    out[t] = num / den;
}

extern "C" void kernel_launch(void* const* d_in, const int* in_sizes, int n_in,
                              void* d_out, int out_size, void* d_ws, size_t ws_size,
                              hipStream_t stream)
{
    const float* Q    = (const float*)d_in[0];
    const float* K    = (const float*)d_in[1];
    const float* V    = (const float*)d_in[2];
    const int*   mask = (const int*)d_in[3];
    const float* Wq   = (const float*)d_in[4];
    const float* bq   = (const float*)d_in[5];
    const float* Wk   = (const float*)d_in[6];
    const float* bk   = (const float*)d_in[7];
    const float* Wv   = (const float*)d_in[8];
    const float* bv   = (const float*)d_in[9];
    float* out = (float*)d_out;

    char* ws = (char*)d_ws;
    u16*   wb   = (u16*)(ws);                          // 384 KB: Wq/Wk/Wv bf16
    u16*   qb   = (u16*)(ws + 393216);                 // 1 MB: q bf16 [8192][64]
    u16*   kb   = (u16*)(ws + 393216 + 1048576);       // 1 MB: k bf16 [8192][64]
    u16*   vtb  = (u16*)(ws + 393216 + 2097152);       // 1 MB: vT bf16 [2][64][4096]
    float* pacc = (float*)(ws + 4194304);              // 16 MB: [512][8][16][64]
    float* pm   = (float*)(ws + 4194304 + 16777216);   // 256 KB
    float* pl   = (float*)(ws + 4194304 + 16777216 + 262144);

    wcvt_kernel<<<96, 256, 0, stream>>>(Wq, Wk, Wv, wb);
    proj_kernel<<<384, 256, 0, stream>>>(Q, K, V, bq, bk, bv, wb, qb, kb, vtb);
    attn_kernel<<<1024, 256, 0, stream>>>(mask, qb, kb, vtb, pacc, pm, pl);
    comb_kernel<<<2048, 256, 0, stream>>>(pacc, pm, pl, out);
}

// Round 3
// 137.640 us; speedup vs baseline: 1.0166x; 1.0166x over previous
//
#include <hip/hip_runtime.h>

typedef unsigned short u16;
typedef unsigned long long u64;
typedef __bf16 bf16x8 __attribute__((ext_vector_type(8)));
typedef float f32x4 __attribute__((ext_vector_type(4)));

#define MFMA16(a, b, c) __builtin_amdgcn_mfma_f32_16x16x32_bf16((a), (b), (c), 0, 0, 0)

__device__ __forceinline__ bf16x8 ld8(const u16* p) {
    return *reinterpret_cast<const bf16x8*>(p);
}

__device__ __forceinline__ unsigned pk2(float a, float b) {
    unsigned short ua = __builtin_bit_cast(unsigned short, (__bf16)a);
    unsigned short ub = __builtin_bit_cast(unsigned short, (__bf16)b);
    return (unsigned)ua | ((unsigned)ub << 16);
}

__device__ __forceinline__ bf16x8 cvt8(float4 a, float4 b) {
    bf16x8 r;
    r[0] = (__bf16)a.x; r[1] = (__bf16)a.y; r[2] = (__bf16)a.z; r[3] = (__bf16)a.w;
    r[4] = (__bf16)b.x; r[5] = (__bf16)b.y; r[6] = (__bf16)b.z; r[7] = (__bf16)b.w;
    return r;
}

// ---------------- Kernel 0: convert Wq/Wk/Wv fp32 -> bf16 ----------------
__global__ __launch_bounds__(256) void wcvt_kernel(
    const float* __restrict__ Wq, const float* __restrict__ Wk,
    const float* __restrict__ Wv, u16* __restrict__ wb)
{
    const int t = blockIdx.x * 256 + threadIdx.x;
    const int mat = t >> 13;
    const int idx = (t & 8191) * 8;
    const float* src = (mat == 0) ? Wq : (mat == 1) ? Wk : Wv;
    float4 a = *(const float4*)(src + idx);
    float4 b = *(const float4*)(src + idx + 4);
    uint4 o;
    o.x = pk2(a.x, a.y); o.y = pk2(a.z, a.w);
    o.z = pk2(b.x, b.y); o.w = pk2(b.z, b.w);
    *reinterpret_cast<uint4*>(wb + (size_t)mat * 65536 + idx) = o;
}

// ---------------- Kernel 1: fused projections (blocks 0..383) + mask bitpack (384..2431) ----
__global__ __launch_bounds__(256) void projpack_kernel(
    const float* __restrict__ Q, const float* __restrict__ K, const float* __restrict__ V,
    const float* __restrict__ bq, const float* __restrict__ bk, const float* __restrict__ bv,
    const u16* __restrict__ wb, const int* __restrict__ mask,
    u16* __restrict__ qb, u16* __restrict__ kb, u16* __restrict__ vtb,
    u64* __restrict__ bits64)
{
    const int lane = threadIdx.x & 63;
    const int w    = threadIdx.x >> 6;

    if (blockIdx.x >= 384) {
        // ---- mask bitpack: one wave per mask row (4096 ints -> 64 u64 words) ----
        // ALL ballots execute fully converged (convergent ops must not sit under
        // divergent control flow -- that was round 2's bug); per-lane selection
        // afterwards is register moves only.
        const int gwv = (blockIdx.x - 384) * 4 + w;          // 0..8191 (= B*S rows)
        const int* mp = mask + (size_t)gwv * 4096 + lane;
        u64* op = bits64 + (size_t)gwv * 64;
        #pragma unroll 1
        for (int step = 0; step < 8; ++step) {
            const int* sp = mp + step * 512;
            const u64 b0 = __ballot(sp[0]   != 0);
            const u64 b1 = __ballot(sp[64]  != 0);
            const u64 b2 = __ballot(sp[128] != 0);
            const u64 b3 = __ballot(sp[192] != 0);
            const u64 b4 = __ballot(sp[256] != 0);
            const u64 b5 = __ballot(sp[320] != 0);
            const u64 b6 = __ballot(sp[384] != 0);
            const u64 b7 = __ballot(sp[448] != 0);
            u64 mine = b0;
            if (lane == 1) mine = b1;
            if (lane == 2) mine = b2;
            if (lane == 3) mine = b3;
            if (lane == 4) mine = b4;
            if (lane == 5) mine = b5;
            if (lane == 6) mine = b6;
            if (lane == 7) mine = b7;
            if (lane < 8) op[step * 8 + lane] = mine;
        }
        return;
    }

    // ---- projections q,k (row-major) and v (transposed) ----
    const int mat  = blockIdx.x >> 7;
    const int tile = blockIdx.x & 127;
    const int c = lane & 15, g = lane >> 4;

    const float* X = (mat == 0) ? Q : (mat == 1) ? K : V;
    const u16*   W = wb + (size_t)mat * 65536;

    const int rw = tile * 64 + w * 16;
    const float* xp = X + (size_t)(rw + c) * 1024 + g * 8;
    const u16*   wp = W + (size_t)c * 1024 + g * 8;

    f32x4 acc[4] = {};
    float4 xa = *(const float4*)xp;
    float4 xb = *(const float4*)(xp + 4);

    #pragma unroll 2
    for (int kk = 0; kk < 32; ++kk) {
        bf16x8 a = cvt8(xa, xb);
        if (kk < 31) {
            xa = *(const float4*)(xp + (kk + 1) * 32);
            xb = *(const float4*)(xp + (kk + 1) * 32 + 4);
        }
        const u16* wk = wp + kk * 32;
        if (mat < 2) {
            #pragma unroll
            for (int t = 0; t < 4; ++t)
                acc[t] = MFMA16(a, ld8(wk + t * 16 * 1024), acc[t]);
        } else {
            #pragma unroll
            for (int t = 0; t < 4; ++t)
                acc[t] = MFMA16(ld8(wk + t * 16 * 1024), a, acc[t]);
        }
    }

    if (mat < 2) {
        const float* bias = (mat == 0) ? bq : bk;
        u16* dst = (mat == 0) ? qb : kb;
        #pragma unroll
        for (int t = 0; t < 4; ++t) {
            const float bz = bias[t * 16 + c];
            #pragma unroll
            for (int r = 0; r < 4; ++r) {
                const int row = rw + g * 4 + r;
                dst[(size_t)row * 64 + t * 16 + c] =
                    __builtin_bit_cast(u16, (__bf16)(acc[t][r] + bz));
            }
        }
    } else {
        const int sg = rw + c;
        const int bidx = sg >> 12, sin = sg & 4095;
        #pragma unroll
        for (int t = 0; t < 4; ++t) {
            #pragma unroll
            for (int r = 0; r < 4; ++r) {
                const int dv = t * 16 + g * 4 + r;
                vtb[(size_t)(bidx * 64 + dv) * 4096 + sin] =
                    __builtin_bit_cast(u16, (__bf16)(acc[t][r] + bv[dv]));
            }
        }
    }
}

// ---------------- Kernel 2: flash attention phase 1 (bitmask, reg-pipelined) ----------------
__global__ __launch_bounds__(256) void attn_kernel(
    const unsigned* __restrict__ bits, const u16* __restrict__ qb,
    const u16* __restrict__ kb, const u16* __restrict__ vtb,
    float* __restrict__ pacc, float* __restrict__ pm, float* __restrict__ pl)
{
    __shared__ uint2 plds[4][128];   // per-wave 16q x 32s bf16, XOR-swizzled
    const int lane = threadIdx.x & 63, w = threadIdx.x >> 6;
    const int c = lane & 15, g = lane >> 4;
    const int gw    = blockIdx.x * 4 + w;
    const int strip = gw >> 3;
    const int chunk = gw & 7;
    const int b     = strip >> 8;
    const int q0    = (strip & 255) * 16;
    const int sBase = chunk * 512;
    const float SSC = 0.18033688011112042f;   // (1/8) * log2(e)

    const u16* qrow = qb + (size_t)((b << 12) + q0 + c) * 64 + g * 8;
    const bf16x8 qf0 = ld8(qrow);
    const bf16x8 qf1 = ld8(qrow + 32);

    // per-lane bases folded once
    const u16* kfp = kb  + (((size_t)b << 12) + sBase + c) * 64 + g * 8;   // + it*2048 per iter
    const u16* vfp = vtb + (size_t)(b * 64 + c) * 4096 + sBase + g * 8;    // + it*32 per iter
    const unsigned* brow = bits + (size_t)((b << 12) + q0 + c) * 128 + (sBase >> 5);

    f32x4 acc0 = {}, acc1 = {}, acc2 = {}, acc3 = {};
    const f32x4 zf = {};
    float m_run = -__builtin_inff(), l_run = 0.f;

    // software pipeline: K frags 1 iter ahead, mask words 2 ahead
    unsigned wA = brow[0], wB = brow[1];
    bf16x8 k00 = ld8(kfp),            k01 = ld8(kfp + 32);
    bf16x8 k10 = ld8(kfp + 16 * 64),  k11 = ld8(kfp + 16 * 64 + 32);

    #pragma unroll 1
    for (int it = 0; it < 16; ++it) {
        // V frags for THIS iter: issued early, consumed after softmax (~400 cyc later)
        const u16* vp = vfp + it * 32;
        const bf16x8 v0 = ld8(vp);
        const bf16x8 v1 = ld8(vp + 16 * 4096);
        const bf16x8 v2 = ld8(vp + 32 * 4096);
        const bf16x8 v3 = ld8(vp + 48 * 4096);

        // QK^T swapped (D[s][q]) with prefetched K regs
        f32x4 d0 = MFMA16(k00, qf0, zf);
        d0 = MFMA16(k01, qf1, d0);
        f32x4 d1 = MFMA16(k10, qf0, zf);
        d1 = MFMA16(k11, qf1, d1);

        // prefetch next iter's K frags
        const int no = (it < 15) ? (it + 1) * 2048 : it * 2048;
        k00 = ld8(kfp + no);            k01 = ld8(kfp + no + 32);
        k10 = ld8(kfp + no + 16 * 64);  k11 = ld8(kfp + no + 16 * 64 + 32);

        // mask word rotation (depth-2 prefetch)
        const unsigned wc_ = wA;
        wA = wB;
        wB = brow[(it + 2 < 16) ? (it + 2) : 15];

        const unsigned s0b = wc_ >> (g * 4);        // bits for s = s0 + g*4 + r
        const unsigned s1b = wc_ >> (16 + g * 4);   // bits for s = s0 + 16 + g*4 + r
        const float x0 = (s0b & 1u) ? d0[0] * SSC : -1e9f;
        const float x1 = (s0b & 2u) ? d0[1] * SSC : -1e9f;
        const float x2 = (s0b & 4u) ? d0[2] * SSC : -1e9f;
        const float x3 = (s0b & 8u) ? d0[3] * SSC : -1e9f;
        const float x4 = (s1b & 1u) ? d1[0] * SSC : -1e9f;
        const float x5 = (s1b & 2u) ? d1[1] * SSC : -1e9f;
        const float x6 = (s1b & 4u) ? d1[2] * SSC : -1e9f;
        const float x7 = (s1b & 8u) ? d1[3] * SSC : -1e9f;

        float tm = fmaxf(fmaxf(fmaxf(x0, x1), fmaxf(x2, x3)),
                         fmaxf(fmaxf(x4, x5), fmaxf(x6, x7)));
        tm = fmaxf(tm, __shfl_xor(tm, 16));
        tm = fmaxf(tm, __shfl_xor(tm, 32));
        const float m_new = fmaxf(m_run, tm);
        const float f = exp2f(m_run - m_new);

        const float p0 = exp2f(x0 - m_new), p1 = exp2f(x1 - m_new);
        const float p2 = exp2f(x2 - m_new), p3 = exp2f(x3 - m_new);
        const float p4 = exp2f(x4 - m_new), p5 = exp2f(x5 - m_new);
        const float p6 = exp2f(x6 - m_new), p7 = exp2f(x7 - m_new);
        float rs = ((p0 + p1) + (p2 + p3)) + ((p4 + p5) + (p6 + p7));
        rs += __shfl_xor(rs, 16);
        rs += __shfl_xor(rs, 32);
        l_run = l_run * f + rs;
        m_run = m_new;

        // P -> LDS (row q=c), 8B chunks XOR-swizzled by (q&7)
        plds[w][c * 8 + ( g      ^ (c & 7))] = make_uint2(pk2(p0, p1), pk2(p2, p3));
        plds[w][c * 8 + ((g + 4) ^ (c & 7))] = make_uint2(pk2(p4, p5), pk2(p6, p7));

        if (__any(f < 1.0f)) {                     // rescale (~20% of iters)
            const float f0 = __shfl(f, g * 4 + 0);
            const float f1 = __shfl(f, g * 4 + 1);
            const float f2 = __shfl(f, g * 4 + 2);
            const float f3 = __shfl(f, g * 4 + 3);
            acc0[0] *= f0; acc0[1] *= f1; acc0[2] *= f2; acc0[3] *= f3;
            acc1[0] *= f0; acc1[1] *= f1; acc1[2] *= f2; acc1[3] *= f3;
            acc2[0] *= f0; acc2[1] *= f1; acc2[2] *= f2; acc2[3] *= f3;
            acc3[0] *= f0; acc3[1] *= f1; acc3[2] *= f2; acc3[3] *= f3;
        }

        // PV: A = P[q=c][s-run g*8..+7] from LDS, B = vT frags already in regs
        union { uint2 u[2]; bf16x8 v; } pa;
        pa.u[0] = plds[w][c * 8 + ((2 * g    ) ^ (c & 7))];
        pa.u[1] = plds[w][c * 8 + ((2 * g + 1) ^ (c & 7))];

        acc0 = MFMA16(pa.v, v0, acc0);
        acc1 = MFMA16(pa.v, v1, acc1);
        acc2 = MFMA16(pa.v, v2, acc2);
        acc3 = MFMA16(pa.v, v3, acc3);
    }

    const size_t pidx = (size_t)(strip * 8 + chunk) * 16;
    #pragma unroll
    for (int r = 0; r < 4; ++r) {
        const size_t row = pidx + g * 4 + r;
        pacc[row * 64 +  0 + c] = acc0[r];
        pacc[row * 64 + 16 + c] = acc1[r];
        pacc[row * 64 + 32 + c] = acc2[r];
        pacc[row * 64 + 48 + c] = acc3[r];
    }
    if (lane < 16) {
        pm[pidx + c] = m_run;
        pl[pidx + c] = l_run;
    }
}

// ---------------- Kernel 3: combine 8 s-chunk partials per row ----------------
__global__ __launch_bounds__(256) void comb_kernel(
    const float* __restrict__ pacc, const float* __restrict__ pm,
    const float* __restrict__ pl, float* __restrict__ out)
{
    const int t = blockIdx.x * 256 + threadIdx.x;
    const int r = t >> 6, dv = t & 63;
    const int strip = r >> 4, qi = r & 15;
    const int base = strip * 128 + qi;
    float mv[8];
    float M = -__builtin_inff();
    #pragma unroll
    for (int cc = 0; cc < 8; ++cc) { mv[cc] = pm[base + cc * 16]; M = fmaxf(M, mv[cc]); }
    float num = 0.f, den = 0.f;
    #pragma unroll
    for (int cc = 0; cc < 8; ++cc) {
        const float wgt = exp2f(mv[cc] - M);
        num += wgt * pacc[(size_t)(base + cc * 16) * 64 + dv];
        den += wgt * pl[base + cc * 16];
    }
    out[t] = num / den;
}

extern "C" void kernel_launch(void* const* d_in, const int* in_sizes, int n_in,
                              void* d_out, int out_size, void* d_ws, size_t ws_size,
                              hipStream_t stream)
{
    const float* Q    = (const float*)d_in[0];
    const float* K    = (const float*)d_in[1];
    const float* V    = (const float*)d_in[2];
    const int*   mask = (const int*)d_in[3];
    const float* Wq   = (const float*)d_in[4];
    const float* bq   = (const float*)d_in[5];
    const float* Wk   = (const float*)d_in[6];
    const float* bk   = (const float*)d_in[7];
    const float* Wv   = (const float*)d_in[8];
    const float* bv   = (const float*)d_in[9];
    float* out = (float*)d_out;

    char* ws = (char*)d_ws;
    u16*   wb   = (u16*)(ws);                            // 384 KB
    u16*   qb   = (u16*)(ws + 393216);                   // 1 MB
    u16*   kb   = (u16*)(ws + 393216 + 1048576);         // 1 MB
    u16*   vtb  = (u16*)(ws + 393216 + 2097152);         // 1 MB
    u64*   bits = (u64*)(ws + 4194304);                  // 4 MB: [8192 rows][64 u64]
    float* pm   = (float*)(ws + 8388608);                // 256 KB
    float* pl   = (float*)(ws + 8388608 + 262144);       // 256 KB
    float* pacc = (float*)(ws + 8388608 + 524288);       // 16 MB

    wcvt_kernel<<<96, 256, 0, stream>>>(Wq, Wk, Wv, wb);
    projpack_kernel<<<2432, 256, 0, stream>>>(Q, K, V, bq, bk, bv, wb, mask,
                                              qb, kb, vtb, bits);
    attn_kernel<<<1024, 256, 0, stream>>>((const unsigned*)bits, qb, kb, vtb, pacc, pm, pl);
    comb_kernel<<<2048, 256, 0, stream>>>(pacc, pm, pl, out);
}